// Round 17
// baseline (124.614 us; speedup 1.0000x reference)
//
#include <hip/hip_runtime.h>
#include <hip/hip_bf16.h>
#include <stdint.h>
#include <stddef.h>

#define NTOK   2048
#define NHEAD  16
#define DHEAD  64
#define DMODEL 1024
#define NROWS  4096      // B * NTOK
#define NQKV   3072
#define RMS_EPS 1.1920928955078125e-07f
// attention scale 1/8 with log2(e) folded in (scores in log2 domain)
#define QSCALE 0.1803368801111204f

typedef short bf16x8 __attribute__((ext_vector_type(8)));
typedef float f32x4  __attribute__((ext_vector_type(4)));
typedef unsigned short u16x4 __attribute__((ext_vector_type(4)));
typedef unsigned short u16x8 __attribute__((ext_vector_type(8)));

__device__ __forceinline__ unsigned short f2b(float f) {
  unsigned u = __builtin_bit_cast(unsigned, f);
  return (unsigned short)((u + 0x7fffu + ((u >> 16) & 1u)) >> 16);  // RNE
}

__device__ __forceinline__ unsigned pk2bf(float a, float b) {
  __hip_bfloat162 h = __float22bfloat162_rn(make_float2(a, b));
  unsigned u;
  __builtin_memcpy(&u, &h, 4);
  return u;
}

__device__ __forceinline__ float fexp2(float x) {
#if __has_builtin(__builtin_amdgcn_exp2f)
  return __builtin_amdgcn_exp2f(x);
#else
  float r;
  asm("v_exp_f32 %0, %1" : "=v"(r) : "v"(x));
  return r;
#endif
}

__device__ __forceinline__ void gl16(const void* g, void* l) {
  __builtin_amdgcn_global_load_lds((__attribute__((address_space(1))) void*)g,
                                   (__attribute__((address_space(3))) void*)l,
                                   16, 0, 0);
}

// ==== fused prep: rmsnorm (blocks 0..4095) + w_qkv transpose (4096..4863)
// ==== + w_o transpose (4864..5119) — one launch, concurrent execution.
__global__ __launch_bounds__(256) void k_prep(
    const float* __restrict__ x, const float* __restrict__ norm_w,
    unsigned short* __restrict__ xn,
    const float* __restrict__ w_qkv, unsigned short* __restrict__ wqkvT,
    const float* __restrict__ w_o, unsigned short* __restrict__ woT) {
  __shared__ float tile[64][65];
  int bid = blockIdx.x;
  int t = threadIdx.x;
  if (bid < NROWS) {
    int row = bid;
    float4 v = ((const float4*)(x + (size_t)row * DMODEL))[t];
    float ss = v.x * v.x + v.y * v.y + v.z * v.z + v.w * v.w;
#pragma unroll
    for (int m = 1; m < 64; m <<= 1) ss += __shfl_xor(ss, m, 64);
    if ((t & 63) == 0) tile[0][t >> 6] = ss;
    __syncthreads();
    float tot = (tile[0][0] + tile[0][1]) + (tile[0][2] + tile[0][3]);
    float rs = rsqrtf(tot * (1.0f / DMODEL) + RMS_EPS);
    float4 wv = ((const float4*)norm_w)[t];
    u16x4 o;
    o.x = f2b(v.x * rs * wv.x);
    o.y = f2b(v.y * rs * wv.y);
    o.z = f2b(v.z * rs * wv.z);
    o.w = f2b(v.w * rs * wv.w);
    *(u16x4*)(xn + (size_t)row * DMODEL + t * 4) = o;
    return;
  }
  const float* W;
  unsigned short* Wt;
  int Nw, bk, bn;
  if (bid < NROWS + 768) {
    int m = bid - NROWS;
    W = w_qkv; Wt = wqkvT; Nw = NQKV;
    bk = (m & 15) * 64; bn = (m >> 4) * 64;
  } else {
    int m = bid - NROWS - 768;
    W = w_o; Wt = woT; Nw = DMODEL;
    bk = (m & 15) * 64; bn = (m >> 4) * 64;
  }
  int tr = t >> 4;
  int tc = (t & 15) * 4;
#pragma unroll
  for (int rr = 0; rr < 64; rr += 16) {
    float4 v = *(const float4*)&W[(size_t)(bk + tr + rr) * Nw + bn + tc];
    tile[tr + rr][tc + 0] = v.x;
    tile[tr + rr][tc + 1] = v.y;
    tile[tr + rr][tc + 2] = v.z;
    tile[tr + rr][tc + 3] = v.w;
  }
  __syncthreads();
#pragma unroll
  for (int rr = 0; rr < 64; rr += 16) {
    int n = bn + tr + rr;
    u16x4 o;
    o.x = f2b(tile[tc + 0][tr + rr]);
    o.y = f2b(tile[tc + 1][tr + rr]);
    o.z = f2b(tile[tc + 2][tr + rr]);
    o.w = f2b(tile[tc + 3][tr + rr]);
    *(u16x4*)&Wt[(size_t)n * DMODEL + bk + tc] = o;
  }
}

// === QKV GEMM: BM=128 BN=64 (one head per block), 4 waves x (32 rows x 64 cols),
// === acc[2][4], 36KB LDS -> 4 blocks/CU, counted-vmcnt(3) 3-buffer pipeline + T2.
#define QSTAGE(b, k0) do {                                   \
    gl16(Ag + (k0), &As[b][t * 8]);                          \
    gl16(Ag + (k0) + 64 * DMODEL, &As[b][(t + 256) * 8]);    \
    gl16(Bg + (k0), &Bs[b][t * 8]);                          \
  } while (0)

__global__ __launch_bounds__(256) void k_qkv_gemm(
    const unsigned short* __restrict__ A, const unsigned short* __restrict__ Bt,
    const float* __restrict__ sin_t, const float* __restrict__ cos_t,
    unsigned short* __restrict__ Qh, unsigned short* __restrict__ Kh,
    unsigned short* __restrict__ VhT) {
  __shared__ unsigned short As[3][128 * 32];
  __shared__ unsigned short Bs[3][64 * 32];
  int bm = blockIdx.x, bn = blockIdx.y;
  int t = threadIdx.x;
  int l = t & 63, w = t >> 6;
  int lr = l & 15, lg = l >> 4;
  f32x4 acc[2][4] = {};

  int srow = t >> 2;
  int scho = ((t & 3) ^ ((t >> 3) & 3)) * 8;          // pre-swizzled source chunk
  const unsigned short* Ag = A + (size_t)(bm * 128 + srow) * DMODEL + scho;
  const unsigned short* Bg = Bt + (size_t)(bn * 64 + srow) * DMODEL + scho;
  int swz = (lr >> 1) & 3;

  QSTAGE(0, 0);
  QSTAGE(1, 32);

  for (int i = 0; i < 32; i++) {
    int cb = i % 3;
    if (i < 31) { asm volatile("s_waitcnt vmcnt(3)" ::: "memory"); }
    else        { asm volatile("s_waitcnt vmcnt(0)" ::: "memory"); }
    __builtin_amdgcn_s_barrier();
    __builtin_amdgcn_sched_barrier(0);
    if (i < 30) QSTAGE((i + 2) % 3, (i + 2) * 32);
    bf16x8 af[2], bfr[4];
#pragma unroll
    for (int ii = 0; ii < 2; ii++)
      af[ii] = *(const bf16x8*)&As[cb][(w * 32 + ii * 16 + lr) * 32 + (lg ^ swz) * 8];
#pragma unroll
    for (int jj = 0; jj < 4; jj++)
      bfr[jj] = *(const bf16x8*)&Bs[cb][(jj * 16 + lr) * 32 + (lg ^ swz) * 8];
    __builtin_amdgcn_s_setprio(1);
#pragma unroll
    for (int ii = 0; ii < 2; ii++)
#pragma unroll
      for (int jj = 0; jj < 4; jj++)
        acc[ii][jj] = __builtin_amdgcn_mfma_f32_16x16x32_bf16(af[ii], bfr[jj], acc[ii][jj], 0, 0, 0);
    __builtin_amdgcn_s_setprio(0);
  }

  int nc0 = bn * 64;
  int which = nc0 >> 10;
  int h = (nc0 & 1023) >> 6;
#pragma unroll
  for (int i = 0; i < 2; i++) {
#pragma unroll
    for (int r = 0; r < 4; r++) {
      int m = bm * 128 + w * 32 + i * 16 + lg * 4 + r;
      int b = m >> 11;
      int n = m & (NTOK - 1);
      if (which == 2) {
#pragma unroll
        for (int j = 0; j < 4; j++) {
          int d = j * 16 + lr;
          VhT[((size_t)((b * NHEAD + h) * DHEAD) + d) * NTOK + n] = f2b(acc[i][j][r]);
        }
      } else {
        size_t obase = ((size_t)(b * NHEAD + h) * NTOK + n) * DHEAD;
        unsigned short* dst = which ? Kh : Qh;
        float qs = which ? 1.0f : QSCALE;
#pragma unroll
        for (int j = 0; j < 2; j++) {
          int d = j * 16 + lr;
          float t1 = acc[i][j][r];
          float t2 = acc[i][j + 2][r];
          float c1 = cos_t[n * DHEAD + d],      s1 = sin_t[n * DHEAD + d];
          float c2 = cos_t[n * DHEAD + d + 32], s2 = sin_t[n * DHEAD + d + 32];
          dst[obase + d]      = f2b((t1 * c1 - t2 * s1) * qs);
          dst[obase + d + 32] = f2b((t2 * c2 + t1 * s2) * qs);
        }
      }
    }
  }
}

// ---- flash attention (causal) with kv-split: 48 work items per bh, sorted desc ----
#define SL(q, a, b) ((q) | ((a) << 6) | ((b) << 12))
__constant__ int SLOTS[48] = {
  SL(31,0,16), SL(31,16,32), SL(30,15,31), SL(15,0,16),
  SL(30,0,15), SL(29,0,15),  SL(29,15,30), SL(28,14,29), SL(14,0,15),
  SL(28,0,14), SL(27,0,14),  SL(27,14,28), SL(26,13,27), SL(13,0,14),
  SL(26,0,13), SL(25,0,13),  SL(25,13,26), SL(24,12,25), SL(12,0,13),
  SL(24,0,12), SL(23,0,12),  SL(23,12,24), SL(22,11,23), SL(11,0,12),
  SL(22,0,11), SL(21,0,11),  SL(21,11,22), SL(20,10,21), SL(10,0,11),
  SL(20,0,10), SL(19,0,10),  SL(19,10,20), SL(18,9,19),  SL(9,0,10),
  SL(18,0,9),  SL(17,0,9),   SL(17,9,18),  SL(16,8,17),  SL(8,0,9),
  SL(16,0,8),  SL(7,0,8),    SL(6,0,7),    SL(5,0,6),    SL(4,0,5),
  SL(3,0,4),   SL(2,0,3),    SL(1,0,2),    SL(0,0,1)
};

__global__ __launch_bounds__(256, 4) void k_attn(
    const unsigned short* __restrict__ Qh, const unsigned short* __restrict__ Kh,
    const unsigned short* __restrict__ VhT, unsigned short* __restrict__ AO,
    unsigned short* __restrict__ Opart, float* __restrict__ Mpart,
    float* __restrict__ Lpart) {
  int bh = blockIdx.x;
  int sv = SLOTS[blockIdx.y];
  int qt = sv & 63, kt0 = (sv >> 6) & 63, kt1 = sv >> 12;
  bool partial = (kt0 != 0) || (kt1 != qt + 1);
  int half = (kt0 != 0) ? 1 : 0;
  int t = threadIdx.x;
  int l = t & 63, w = t >> 6;
  int lr = l & 15, lg = l >> 4;

  __shared__ unsigned short Ks[2][64 * 64];
  __shared__ unsigned short Vs[2][64 * 64];
  __shared__ unsigned short Ps[4][16 * 64];

  const unsigned short* Qb = Qh  + (size_t)bh * NTOK * DHEAD;
  const unsigned short* Kb = Kh  + (size_t)bh * NTOK * DHEAD;
  const unsigned short* Vb = VhT + (size_t)bh * DHEAD * NTOK;

  int qrow = qt * 64 + w * 16 + lr;
  bf16x8 aq0 = *(const bf16x8*)&Qb[(size_t)qrow * DHEAD + lg * 8];
  bf16x8 aq1 = *(const bf16x8*)&Qb[(size_t)qrow * DHEAD + 32 + lg * 8];

  f32x4 accO[4] = {};
  float mrow = -1e38f;
  float lsum = 0.f;

  int srow = t >> 3;
  int spc  = t & 7;
  int sc0  = (spc ^ (srow & 7)) * 8;
  int sc1  = (spc ^ ((srow + 32) & 7)) * 8;

  int koff[4][2], voff[2][4], poff[2], pwoff[4];
#pragma unroll
  for (int nf = 0; nf < 4; nf++) {
    int krow = nf * 16 + lr;
    koff[nf][0] = krow * 128 + ((lg * 16) ^ ((krow & 7) << 4));
    koff[nf][1] = krow * 128 + ((lg * 16 + 64) ^ ((krow & 7) << 4));
    pwoff[nf] = lr * 128 + ((nf * 32 + lg * 8) ^ ((lr & 7) << 4));
  }
#pragma unroll
  for (int ks = 0; ks < 2; ks++) {
    poff[ks] = lr * 128 + ((lg * 16 + ks * 64) ^ ((lr & 7) << 4));
#pragma unroll
    for (int df = 0; df < 4; df++) {
      int col = df * 16 + lr;
      voff[ks][df] = col * 128 + ((lg * 16 + ks * 64) ^ ((col & 7) << 4));
    }
  }

  {
    int kv0 = kt0 * 64;
    gl16(Kb + (size_t)(kv0 + srow) * DHEAD + sc0, &Ks[0][t * 8]);
    gl16(Kb + (size_t)(kv0 + srow + 32) * DHEAD + sc1, &Ks[0][(t + 256) * 8]);
    gl16(Vb + (size_t)srow * NTOK + kv0 + sc0, &Vs[0][t * 8]);
    gl16(Vb + (size_t)(srow + 32) * NTOK + kv0 + sc1, &Vs[0][(t + 256) * 8]);
  }
  __syncthreads();

  for (int kt = kt0; kt < kt1; ++kt) {
    int cur = (kt - kt0) & 1, nxt = cur ^ 1;
    int kv0 = kt * 64;

    if (kt + 1 < kt1) {
      int kvn = kv0 + 64;
      gl16(Kb + (size_t)(kvn + srow) * DHEAD + sc0, &Ks[nxt][t * 8]);
      gl16(Kb + (size_t)(kvn + srow + 32) * DHEAD + sc1, &Ks[nxt][(t + 256) * 8]);
      gl16(Vb + (size_t)srow * NTOK + kvn + sc0, &Vs[nxt][t * 8]);
      gl16(Vb + (size_t)(srow + 32) * NTOK + kvn + sc1, &Vs[nxt][(t + 256) * 8]);
    }

    // ---- S^T = K Q^T
    const char* kb = (const char*)Ks[cur];
    f32x4 s[4];
    __builtin_amdgcn_s_setprio(1);
#pragma unroll
    for (int nf = 0; nf < 4; nf++) {
      bf16x8 bk0 = *(const bf16x8*)(kb + koff[nf][0]);
      bf16x8 bk1 = *(const bf16x8*)(kb + koff[nf][1]);
      f32x4 z = {};
      z = __builtin_amdgcn_mfma_f32_16x16x32_bf16(bk0, aq0, z, 0, 0, 0);
      s[nf] = __builtin_amdgcn_mfma_f32_16x16x32_bf16(bk1, aq1, z, 0, 0, 0);
    }
    __builtin_amdgcn_s_setprio(0);

    if (kt == qt) {
      int qr = qt * 64 + w * 16 + lr;
#pragma unroll
      for (int nf = 0; nf < 4; nf++)
#pragma unroll
        for (int r = 0; r < 4; r++)
          if (kv0 + nf * 16 + lg * 4 + r > qr) s[nf][r] = -1e30f;
    }

    // ---- online softmax: in-lane max only; cross-lane reduce deferred
    float t1m = fmaxf(fmaxf(s[0][0], s[0][1]), s[0][2]);
    float t2m = fmaxf(fmaxf(s[0][3], s[1][0]), s[1][1]);
    float t3m = fmaxf(fmaxf(s[1][2], s[1][3]), s[2][0]);
    float t4m = fmaxf(fmaxf(s[2][1], s[2][2]), s[2][3]);
    float t5m = fmaxf(fmaxf(s[3][0], s[3][1]), s[3][2]);
    float pl = fmaxf(fmaxf(fmaxf(t1m, t2m), t3m), fmaxf(fmaxf(t4m, t5m), s[3][3]));
    if (__any(pl > mrow + 8.0f)) {
      float pm = fmaxf(pl, __shfl_xor(pl, 16, 64));
      pm = fmaxf(pm, __shfl_xor(pm, 32, 64));
      float mnew = fmaxf(mrow, pm);
      float corr = fexp2(mrow - mnew);
      mrow = mnew;
      lsum *= corr;
      float c0 = __shfl(corr, lg * 4 + 0, 64);
      float c1 = __shfl(corr, lg * 4 + 1, 64);
      float c2 = __shfl(corr, lg * 4 + 2, 64);
      float c3 = __shfl(corr, lg * 4 + 3, 64);
#pragma unroll
      for (int df = 0; df < 4; df++) {
        accO[df][0] *= c0; accO[df][1] *= c1;
        accO[df][2] *= c2; accO[df][3] *= c3;
      }
    }
    {
      float m = mrow;
      float sum = 0.f;
      char* pw = (char*)Ps[w];
#pragma unroll
      for (int nf = 0; nf < 4; nf++) {
        float p0 = fexp2(s[nf][0] - m);
        float p1 = fexp2(s[nf][1] - m);
        float p2 = fexp2(s[nf][2] - m);
        float p3 = fexp2(s[nf][3] - m);
        sum += (p0 + p1) + (p2 + p3);
        unsigned w0 = pk2bf(p0, p1);
        unsigned w1 = pk2bf(p2, p3);
        *(uint64_t*)(pw + pwoff[nf]) = (uint64_t)w0 | ((uint64_t)w1 << 32);
      }
      lsum += sum;
    }

    // ---- O += P V
    const char* pb = (const char*)Ps[w];
    const char* vb = (const char*)Vs[cur];
    __builtin_amdgcn_s_setprio(1);
#pragma unroll
    for (int ks = 0; ks < 2; ks++) {
      bf16x8 ap = *(const bf16x8*)(pb + poff[ks]);
#pragma unroll
      for (int df = 0; df < 4; df++) {
        bf16x8 bv = *(const bf16x8*)(vb + voff[ks][df]);
        accO[df] = __builtin_amdgcn_mfma_f32_16x16x32_bf16(ap, bv, accO[df], 0, 0, 0);
      }
    }
    __builtin_amdgcn_s_setprio(0);
    __syncthreads();
  }

  // ---- epilogue: reduce per-lane lsum across the 4 lanes of each row
  lsum += __shfl_xor(lsum, 16, 64);
  lsum += __shfl_xor(lsum, 32, 64);

  if (partial) {
    int pbase = (((bh << 4) + (qt - 16)) << 1) + half;
    if (lg == 0) {
      Mpart[pbase * 64 + w * 16 + lr] = mrow;
      Lpart[pbase * 64 + w * 16 + lr] = lsum;
    }
    unsigned short* Od = Opart + (size_t)pbase * 4096;
#pragma unroll
    for (int df = 0; df < 4; df++)
#pragma unroll
      for (int r = 0; r < 4; r++)
        Od[(w * 16 + lg * 4 + r) * 64 + df * 16 + lr] = f2b(accO[df][r]);
  } else {
    int b = bh >> 4, h = bh & 15;
    float li = 1.0f / lsum;
    float l0 = __shfl(li, lg * 4 + 0, 64);
    float l1 = __shfl(li, lg * 4 + 1, 64);
    float l2 = __shfl(li, lg * 4 + 2, 64);
    float l3 = __shfl(li, lg * 4 + 3, 64);
    int qbase = qt * 64 + w * 16;
#pragma unroll
    for (int df = 0; df < 4; df++) {
      int d = df * 16 + lr;
      size_t ob = ((size_t)(b * NTOK + qbase + lg * 4)) * DMODEL + h * DHEAD + d;
      AO[ob + 0 * DMODEL] = f2b(accO[df][0] * l0);
      AO[ob + 1 * DMODEL] = f2b(accO[df][1] * l1);
      AO[ob + 2 * DMODEL] = f2b(accO[df][2] * l2);
      AO[ob + 3 * DMODEL] = f2b(accO[df][3] * l3);
    }
  }
}

// ---- merge two kv-halves for qt>=16 ----
__global__ __launch_bounds__(256) void k_merge(const unsigned short* __restrict__ Opart,
                                               const float* __restrict__ Mpart,
                                               const float* __restrict__ Lpart,
                                               unsigned short* __restrict__ AO) {
  int bh = blockIdx.x, qq = blockIdx.y;
  int t = threadIdx.x;
  int row = t >> 2, d0 = (t & 3) << 4;
  int p0 = ((bh << 4) + qq) << 1;
  float m1 = Mpart[p0 * 64 + row],       l1 = Lpart[p0 * 64 + row];
  float m2 = Mpart[(p0 + 1) * 64 + row], l2 = Lpart[(p0 + 1) * 64 + row];
  float mm = fmaxf(m1, m2);
  float s1 = fexp2(m1 - mm), s2 = fexp2(m2 - mm);
  float li = 1.0f / (l1 * s1 + l2 * s2);
  float a1 = s1 * li, a2 = s2 * li;
  const unsigned short* O1 = Opart + (size_t)p0 * 4096 + row * 64 + d0;
  const unsigned short* O2 = O1 + 4096;
  int qt = 16 + qq;
  int b = bh >> 4, h = bh & 15;
  unsigned short* dst = AO + ((size_t)(b * NTOK + qt * 64 + row)) * DMODEL + h * DHEAD + d0;
#pragma unroll
  for (int c = 0; c < 2; c++) {
    u16x8 v1 = *(const u16x8*)(O1 + c * 8);
    u16x8 v2 = *(const u16x8*)(O2 + c * 8);
    u16x8 o;
#pragma unroll
    for (int e = 0; e < 8; e++) {
      float f1 = __builtin_bit_cast(float, (unsigned)v1[e] << 16);
      float g1 = __builtin_bit_cast(float, (unsigned)v2[e] << 16);
      o[e] = f2b(f1 * a1 + g1 * a2);
    }
    *(u16x8*)(dst + c * 8) = o;
  }
}

// ---- out GEMM: BM=128 BN=64, depth-2 counted-vmcnt pipeline + T2 swizzle ----
#define OSTAGE(b, k0) do {                                   \
    gl16(Ag + (k0), &As[b][t * 8]);                          \
    gl16(Ag + (k0) + 64 * DMODEL, &As[b][(t + 256) * 8]);    \
    gl16(Bg + (k0), &Bs[b][t * 8]);                          \
  } while (0)

__global__ __launch_bounds__(256) void k_out_gemm(
    const unsigned short* __restrict__ A, const unsigned short* __restrict__ Bt,
    const float* __restrict__ bias, float* __restrict__ out) {
  __shared__ unsigned short As[3][128 * 32];
  __shared__ unsigned short Bs[3][64 * 32];
  int bm = blockIdx.x, bn = blockIdx.y;
  int t = threadIdx.x;
  int l = t & 63, w = t >> 6;
  int wr = w >> 1, wc = w & 1;
  int lr = l & 15, lg = l >> 4;
  f32x4 acc[4][2] = {};

  int srow = t >> 2;
  int scho = ((t & 3) ^ ((t >> 3) & 3)) * 8;
  const unsigned short* Ag = A + (size_t)(bm * 128 + srow) * DMODEL + scho;
  const unsigned short* Bg = Bt + (size_t)(bn * 64 + srow) * DMODEL + scho;
  int swz = (lr >> 1) & 3;

  OSTAGE(0, 0);
  OSTAGE(1, 32);

  for (int i = 0; i < 32; i++) {
    int cb = i % 3;
    if (i < 31) { asm volatile("s_waitcnt vmcnt(3)" ::: "memory"); }
    else        { asm volatile("s_waitcnt vmcnt(0)" ::: "memory"); }
    __builtin_amdgcn_s_barrier();
    __builtin_amdgcn_sched_barrier(0);
    if (i < 30) OSTAGE((i + 2) % 3, (i + 2) * 32);
    bf16x8 af[4], bfr[2];
#pragma unroll
    for (int ii = 0; ii < 4; ii++)
      af[ii] = *(const bf16x8*)&As[cb][(wr * 64 + ii * 16 + lr) * 32 + (lg ^ swz) * 8];
#pragma unroll
    for (int jj = 0; jj < 2; jj++)
      bfr[jj] = *(const bf16x8*)&Bs[cb][(wc * 32 + jj * 16 + lr) * 32 + (lg ^ swz) * 8];
    __builtin_amdgcn_s_setprio(1);
#pragma unroll
    for (int ii = 0; ii < 4; ii++)
#pragma unroll
      for (int jj = 0; jj < 2; jj++)
        acc[ii][jj] = __builtin_amdgcn_mfma_f32_16x16x32_bf16(af[ii], bfr[jj], acc[ii][jj], 0, 0, 0);
    __builtin_amdgcn_s_setprio(0);
  }
  int nc0 = bn * 64 + wc * 32;
#pragma unroll
  for (int i = 0; i < 4; i++)
#pragma unroll
    for (int r = 0; r < 4; r++) {
      int m = bm * 128 + wr * 64 + i * 16 + lg * 4 + r;
      float* orow = out + (size_t)m * DMODEL;
#pragma unroll
      for (int j = 0; j < 2; j++) {
        int col = nc0 + j * 16 + lr;
        orow[col] = acc[i][j][r] + bias[col];
      }
    }
}

extern "C" void kernel_launch(void* const* d_in, const int* in_sizes, int n_in,
                              void* d_out, int out_size, void* d_ws, size_t ws_size,
                              hipStream_t stream) {
  const float* x      = (const float*)d_in[0];
  const float* norm_w = (const float*)d_in[1];
  const float* w_qkv  = (const float*)d_in[2];
  const float* w_o    = (const float*)d_in[3];
  const float* b_o    = (const float*)d_in[4];
  const float* sin_t  = (const float*)d_in[5];
  const float* cos_t  = (const float*)d_in[6];
  float* out = (float*)d_out;

  char* ws = (char*)d_ws;
  unsigned short* xn    = (unsigned short*)(ws + (0u << 20));   // 8 MB  (dead after qkv)
  unsigned short* wqkvT = (unsigned short*)(ws + (8u << 20));   // 6 MB  (dead after qkv)
  unsigned short* woT   = (unsigned short*)(ws + (14u << 20));  // 2 MB
  unsigned short* Qh    = (unsigned short*)(ws + (16u << 20));  // 8 MB  [b][h][n][d]
  unsigned short* Kh    = (unsigned short*)(ws + (24u << 20));  // 8 MB  [b][h][n][d]
  unsigned short* VhT   = (unsigned short*)(ws + (32u << 20));  // 8 MB  [b][h][d][n]
  unsigned short* AO    = (unsigned short*)(ws + (40u << 20));  // 8 MB  [b][n][h*d]
  // attn partials reuse regions dead during k_attn (rewritten every call):
  unsigned short* Opart = (unsigned short*)(ws + (0u << 20));           // 8 MB in xn
  float*          Mpart = (float*)(ws + (8u << 20));                    // 256 KB in wqkvT
  float*          Lpart = (float*)(ws + (8u << 20) + (1u << 18));       // 256 KB in wqkvT

  hipLaunchKernelGGL(k_prep, dim3(NROWS + 768 + 256), dim3(256), 0, stream,
                     x, norm_w, xn, w_qkv, wqkvT, w_o, woT);
  hipLaunchKernelGGL(k_qkv_gemm, dim3(32, 48), dim3(256), 0, stream, xn, wqkvT, sin_t, cos_t, Qh, Kh, VhT);
  hipLaunchKernelGGL(k_attn, dim3(32, 48), dim3(256), 0, stream, Qh, Kh, VhT, AO, Opart, Mpart, Lpart);
  hipLaunchKernelGGL(k_merge, dim3(32, 16), dim3(256), 0, stream, Opart, Mpart, Lpart, AO);
  hipLaunchKernelGGL(k_out_gemm, dim3(32, 16), dim3(256), 0, stream, AO, woT, b_o, out);
}

// Round 18
// 113.330 us; speedup vs baseline: 1.0996x; 1.0996x over previous
//
#include <hip/hip_runtime.h>
#include <hip/hip_bf16.h>
#include <stdint.h>
#include <stddef.h>

#define NTOK   2048
#define NHEAD  16
#define DHEAD  64
#define DMODEL 1024
#define NROWS  4096      // B * NTOK
#define NQKV   3072
#define RMS_EPS 1.1920928955078125e-07f
// attention scale 1/8 with log2(e) folded in (scores in log2 domain)
#define QSCALE 0.1803368801111204f

typedef short bf16x8 __attribute__((ext_vector_type(8)));
typedef float f32x4  __attribute__((ext_vector_type(4)));
typedef unsigned short u16x4 __attribute__((ext_vector_type(4)));
typedef unsigned short u16x8 __attribute__((ext_vector_type(8)));

__device__ __forceinline__ unsigned short f2b(float f) {
  unsigned u = __builtin_bit_cast(unsigned, f);
  return (unsigned short)((u + 0x7fffu + ((u >> 16) & 1u)) >> 16);  // RNE
}

__device__ __forceinline__ unsigned pk2bf(float a, float b) {
  __hip_bfloat162 h = __float22bfloat162_rn(make_float2(a, b));
  unsigned u;
  __builtin_memcpy(&u, &h, 4);
  return u;
}

__device__ __forceinline__ float fexp2(float x) {
#if __has_builtin(__builtin_amdgcn_exp2f)
  return __builtin_amdgcn_exp2f(x);
#else
  float r;
  asm("v_exp_f32 %0, %1" : "=v"(r) : "v"(x));
  return r;
#endif
}

__device__ __forceinline__ void gl16(const void* g, void* l) {
  __builtin_amdgcn_global_load_lds((__attribute__((address_space(1))) void*)g,
                                   (__attribute__((address_space(3))) void*)l,
                                   16, 0, 0);
}

// ==== fused prep: rmsnorm (blocks 0..4095) + w_qkv transpose (4096..4863)
// ==== + w_o transpose (4864..5119) — one launch, concurrent execution.
__global__ __launch_bounds__(256) void k_prep(
    const float* __restrict__ x, const float* __restrict__ norm_w,
    unsigned short* __restrict__ xn,
    const float* __restrict__ w_qkv, unsigned short* __restrict__ wqkvT,
    const float* __restrict__ w_o, unsigned short* __restrict__ woT) {
  __shared__ float tile[64][65];
  int bid = blockIdx.x;
  int t = threadIdx.x;
  if (bid < NROWS) {
    // ---- rmsnorm row
    int row = bid;
    float4 v = ((const float4*)(x + (size_t)row * DMODEL))[t];
    float ss = v.x * v.x + v.y * v.y + v.z * v.z + v.w * v.w;
#pragma unroll
    for (int m = 1; m < 64; m <<= 1) ss += __shfl_xor(ss, m, 64);
    if ((t & 63) == 0) tile[0][t >> 6] = ss;
    __syncthreads();
    float tot = (tile[0][0] + tile[0][1]) + (tile[0][2] + tile[0][3]);
    float rs = rsqrtf(tot * (1.0f / DMODEL) + RMS_EPS);
    float4 wv = ((const float4*)norm_w)[t];
    u16x4 o;
    o.x = f2b(v.x * rs * wv.x);
    o.y = f2b(v.y * rs * wv.y);
    o.z = f2b(v.z * rs * wv.z);
    o.w = f2b(v.w * rs * wv.w);
    *(u16x4*)(xn + (size_t)row * DMODEL + t * 4) = o;
    return;
  }
  // ---- transpose+convert: W fp32 [K][Nw] -> Wt bf16 [Nw][K]
  const float* W;
  unsigned short* Wt;
  int Nw, bk, bn;
  if (bid < NROWS + 768) {
    int m = bid - NROWS;
    W = w_qkv; Wt = wqkvT; Nw = NQKV;
    bk = (m & 15) * 64; bn = (m >> 4) * 64;
  } else {
    int m = bid - NROWS - 768;
    W = w_o; Wt = woT; Nw = DMODEL;
    bk = (m & 15) * 64; bn = (m >> 4) * 64;
  }
  int tr = t >> 4;
  int tc = (t & 15) * 4;
#pragma unroll
  for (int rr = 0; rr < 64; rr += 16) {
    float4 v = *(const float4*)&W[(size_t)(bk + tr + rr) * Nw + bn + tc];
    tile[tr + rr][tc + 0] = v.x;
    tile[tr + rr][tc + 1] = v.y;
    tile[tr + rr][tc + 2] = v.z;
    tile[tr + rr][tc + 3] = v.w;
  }
  __syncthreads();
#pragma unroll
  for (int rr = 0; rr < 64; rr += 16) {
    int n = bn + tr + rr;
    u16x4 o;
    o.x = f2b(tile[tc + 0][tr + rr]);
    o.y = f2b(tile[tc + 1][tr + rr]);
    o.z = f2b(tile[tc + 2][tr + rr]);
    o.w = f2b(tile[tc + 3][tr + rr]);
    *(u16x4*)&Wt[(size_t)n * DMODEL + bk + tc] = o;
  }
}

// ------- QKV GEMM: 128x128, BK=32, depth-2 counted-vmcnt pipeline + T2 swizzle -------
// (Proven optimum: ~46 us, 0 bank conflicts, 3 blocks/CU; all geometry variants regressed.)
#define QSTAGE(b, k0) do {                                   \
    gl16(Ag + (k0), &As[b][t * 8]);                          \
    gl16(Ag + (k0) + 64 * DMODEL, &As[b][(t + 256) * 8]);    \
    gl16(Bg + (k0), &Bs[b][t * 8]);                          \
    gl16(Bg + (k0) + 64 * DMODEL, &Bs[b][(t + 256) * 8]);    \
  } while (0)

__global__ __launch_bounds__(256) void k_qkv_gemm(
    const unsigned short* __restrict__ A, const unsigned short* __restrict__ Bt,
    const float* __restrict__ sin_t, const float* __restrict__ cos_t,
    unsigned short* __restrict__ Qh, unsigned short* __restrict__ Kh,
    unsigned short* __restrict__ VhT) {
  __shared__ unsigned short As[3][128 * 32];
  __shared__ unsigned short Bs[3][128 * 32];
  int bm = blockIdx.x, bn = blockIdx.y;
  int t = threadIdx.x;
  int l = t & 63, w = t >> 6;
  int wr = w >> 1, wc = w & 1;
  int lr = l & 15, lg = l >> 4;
  f32x4 acc[4][4] = {};

  int srow = t >> 2;
  int scho = ((t & 3) ^ ((t >> 3) & 3)) * 8;          // pre-swizzled source chunk
  const unsigned short* Ag = A + (size_t)(bm * 128 + srow) * DMODEL + scho;
  const unsigned short* Bg = Bt + (size_t)(bn * 128 + srow) * DMODEL + scho;
  int swz = (lr >> 1) & 3;

  QSTAGE(0, 0);
  QSTAGE(1, 32);

  for (int i = 0; i < 32; i++) {
    int cb = i % 3;
    if (i < 31) { asm volatile("s_waitcnt vmcnt(4)" ::: "memory"); }
    else        { asm volatile("s_waitcnt vmcnt(0)" ::: "memory"); }
    __builtin_amdgcn_s_barrier();
    __builtin_amdgcn_sched_barrier(0);
    if (i < 30) QSTAGE((i + 2) % 3, (i + 2) * 32);
    bf16x8 af[4], bfr[4];
#pragma unroll
    for (int ii = 0; ii < 4; ii++)
      af[ii] = *(const bf16x8*)&As[cb][(wr * 64 + ii * 16 + lr) * 32 + (lg ^ swz) * 8];
#pragma unroll
    for (int jj = 0; jj < 4; jj++)
      bfr[jj] = *(const bf16x8*)&Bs[cb][(wc * 64 + jj * 16 + lr) * 32 + (lg ^ swz) * 8];
#pragma unroll
    for (int ii = 0; ii < 4; ii++)
#pragma unroll
      for (int jj = 0; jj < 4; jj++)
        acc[ii][jj] = __builtin_amdgcn_mfma_f32_16x16x32_bf16(af[ii], bfr[jj], acc[ii][jj], 0, 0, 0);
  }

  int nc0 = bn * 128 + wc * 64;
  int which = nc0 >> 10;
  int h = (nc0 & 1023) >> 6;
#pragma unroll
  for (int i = 0; i < 4; i++) {
#pragma unroll
    for (int r = 0; r < 4; r++) {
      int m = bm * 128 + wr * 64 + i * 16 + lg * 4 + r;
      int b = m >> 11;
      int n = m & (NTOK - 1);
      if (which == 2) {
#pragma unroll
        for (int j = 0; j < 4; j++) {
          int d = j * 16 + lr;
          VhT[((size_t)((b * NHEAD + h) * DHEAD) + d) * NTOK + n] = f2b(acc[i][j][r]);
        }
      } else {
        size_t obase = ((size_t)(b * NHEAD + h) * NTOK + n) * DHEAD;
        unsigned short* dst = which ? Kh : Qh;
        float qs = which ? 1.0f : QSCALE;
#pragma unroll
        for (int j = 0; j < 2; j++) {
          int d = j * 16 + lr;
          float t1 = acc[i][j][r];
          float t2 = acc[i][j + 2][r];
          float c1 = cos_t[n * DHEAD + d],      s1 = sin_t[n * DHEAD + d];
          float c2 = cos_t[n * DHEAD + d + 32], s2 = sin_t[n * DHEAD + d + 32];
          dst[obase + d]      = f2b((t1 * c1 - t2 * s1) * qs);
          dst[obase + d + 32] = f2b((t2 * c2 + t1 * s2) * qs);
        }
      }
    }
  }
}

// ---- flash attention (causal) with kv-split: 48 work items per bh, sorted desc ----
// QBLK=64 proven structure + deferred cross-lane max + per-lane lsum.
#define SL(q, a, b) ((q) | ((a) << 6) | ((b) << 12))
__constant__ int SLOTS[48] = {
  SL(31,0,16), SL(31,16,32), SL(30,15,31), SL(15,0,16),
  SL(30,0,15), SL(29,0,15),  SL(29,15,30), SL(28,14,29), SL(14,0,15),
  SL(28,0,14), SL(27,0,14),  SL(27,14,28), SL(26,13,27), SL(13,0,14),
  SL(26,0,13), SL(25,0,13),  SL(25,13,26), SL(24,12,25), SL(12,0,13),
  SL(24,0,12), SL(23,0,12),  SL(23,12,24), SL(22,11,23), SL(11,0,12),
  SL(22,0,11), SL(21,0,11),  SL(21,11,22), SL(20,10,21), SL(10,0,11),
  SL(20,0,10), SL(19,0,10),  SL(19,10,20), SL(18,9,19),  SL(9,0,10),
  SL(18,0,9),  SL(17,0,9),   SL(17,9,18),  SL(16,8,17),  SL(8,0,9),
  SL(16,0,8),  SL(7,0,8),    SL(6,0,7),    SL(5,0,6),    SL(4,0,5),
  SL(3,0,4),   SL(2,0,3),    SL(1,0,2),    SL(0,0,1)
};

__global__ __launch_bounds__(256, 4) void k_attn(
    const unsigned short* __restrict__ Qh, const unsigned short* __restrict__ Kh,
    const unsigned short* __restrict__ VhT, unsigned short* __restrict__ AO,
    unsigned short* __restrict__ Opart, float* __restrict__ Mpart,
    float* __restrict__ Lpart) {
  int bh = blockIdx.x;
  int sv = SLOTS[blockIdx.y];
  int qt = sv & 63, kt0 = (sv >> 6) & 63, kt1 = sv >> 12;
  bool partial = (kt0 != 0) || (kt1 != qt + 1);
  int half = (kt0 != 0) ? 1 : 0;
  int t = threadIdx.x;
  int l = t & 63, w = t >> 6;
  int lr = l & 15, lg = l >> 4;

  __shared__ unsigned short Ks[2][64 * 64];
  __shared__ unsigned short Vs[2][64 * 64];
  __shared__ unsigned short Ps[4][16 * 64];

  const unsigned short* Qb = Qh  + (size_t)bh * NTOK * DHEAD;
  const unsigned short* Kb = Kh  + (size_t)bh * NTOK * DHEAD;
  const unsigned short* Vb = VhT + (size_t)bh * DHEAD * NTOK;

  int qrow = qt * 64 + w * 16 + lr;
  bf16x8 aq0 = *(const bf16x8*)&Qb[(size_t)qrow * DHEAD + lg * 8];
  bf16x8 aq1 = *(const bf16x8*)&Qb[(size_t)qrow * DHEAD + 32 + lg * 8];

  f32x4 accO[4] = {};
  float mrow = -1e38f;    // running max (log2 domain), row-uniform invariant
  float lsum = 0.f;       // per-lane partial; reduced at epilogue

  int srow = t >> 3;
  int spc  = t & 7;
  int sc0  = (spc ^ (srow & 7)) * 8;
  int sc1  = (spc ^ ((srow + 32) & 7)) * 8;

  int koff[4][2], voff[2][4], poff[2], pwoff[4];
#pragma unroll
  for (int nf = 0; nf < 4; nf++) {
    int krow = nf * 16 + lr;
    koff[nf][0] = krow * 128 + ((lg * 16) ^ ((krow & 7) << 4));
    koff[nf][1] = krow * 128 + ((lg * 16 + 64) ^ ((krow & 7) << 4));
    pwoff[nf] = lr * 128 + ((nf * 32 + lg * 8) ^ ((lr & 7) << 4));
  }
#pragma unroll
  for (int ks = 0; ks < 2; ks++) {
    poff[ks] = lr * 128 + ((lg * 16 + ks * 64) ^ ((lr & 7) << 4));
#pragma unroll
    for (int df = 0; df < 4; df++) {
      int col = df * 16 + lr;
      voff[ks][df] = col * 128 + ((lg * 16 + ks * 64) ^ ((col & 7) << 4));
    }
  }

  {
    int kv0 = kt0 * 64;
    gl16(Kb + (size_t)(kv0 + srow) * DHEAD + sc0, &Ks[0][t * 8]);
    gl16(Kb + (size_t)(kv0 + srow + 32) * DHEAD + sc1, &Ks[0][(t + 256) * 8]);
    gl16(Vb + (size_t)srow * NTOK + kv0 + sc0, &Vs[0][t * 8]);
    gl16(Vb + (size_t)(srow + 32) * NTOK + kv0 + sc1, &Vs[0][(t + 256) * 8]);
  }
  __syncthreads();

  for (int kt = kt0; kt < kt1; ++kt) {
    int cur = (kt - kt0) & 1, nxt = cur ^ 1;
    int kv0 = kt * 64;

    if (kt + 1 < kt1) {
      int kvn = kv0 + 64;
      gl16(Kb + (size_t)(kvn + srow) * DHEAD + sc0, &Ks[nxt][t * 8]);
      gl16(Kb + (size_t)(kvn + srow + 32) * DHEAD + sc1, &Ks[nxt][(t + 256) * 8]);
      gl16(Vb + (size_t)srow * NTOK + kvn + sc0, &Vs[nxt][t * 8]);
      gl16(Vb + (size_t)(srow + 32) * NTOK + kvn + sc1, &Vs[nxt][(t + 256) * 8]);
    }

    // ---- S^T = K Q^T
    const char* kb = (const char*)Ks[cur];
    f32x4 s[4];
    __builtin_amdgcn_s_setprio(1);
#pragma unroll
    for (int nf = 0; nf < 4; nf++) {
      bf16x8 bk0 = *(const bf16x8*)(kb + koff[nf][0]);
      bf16x8 bk1 = *(const bf16x8*)(kb + koff[nf][1]);
      f32x4 z = {};
      z = __builtin_amdgcn_mfma_f32_16x16x32_bf16(bk0, aq0, z, 0, 0, 0);
      s[nf] = __builtin_amdgcn_mfma_f32_16x16x32_bf16(bk1, aq1, z, 0, 0, 0);
    }
    __builtin_amdgcn_s_setprio(0);

    if (kt == qt) {
      int qr = qt * 64 + w * 16 + lr;
#pragma unroll
      for (int nf = 0; nf < 4; nf++)
#pragma unroll
        for (int r = 0; r < 4; r++)
          if (kv0 + nf * 16 + lg * 4 + r > qr) s[nf][r] = -1e30f;
    }

    // ---- online softmax: in-lane max only; cross-lane reduce deferred
    float t1m = fmaxf(fmaxf(s[0][0], s[0][1]), s[0][2]);
    float t2m = fmaxf(fmaxf(s[0][3], s[1][0]), s[1][1]);
    float t3m = fmaxf(fmaxf(s[1][2], s[1][3]), s[2][0]);
    float t4m = fmaxf(fmaxf(s[2][1], s[2][2]), s[2][3]);
    float t5m = fmaxf(fmaxf(s[3][0], s[3][1]), s[3][2]);
    float pl = fmaxf(fmaxf(fmaxf(t1m, t2m), t3m), fmaxf(fmaxf(t4m, t5m), s[3][3]));
    if (__any(pl > mrow + 8.0f)) {
      float pm = fmaxf(pl, __shfl_xor(pl, 16, 64));
      pm = fmaxf(pm, __shfl_xor(pm, 32, 64));
      float mnew = fmaxf(mrow, pm);
      float corr = fexp2(mrow - mnew);
      mrow = mnew;
      lsum *= corr;
      float c0 = __shfl(corr, lg * 4 + 0, 64);
      float c1 = __shfl(corr, lg * 4 + 1, 64);
      float c2 = __shfl(corr, lg * 4 + 2, 64);
      float c3 = __shfl(corr, lg * 4 + 3, 64);
#pragma unroll
      for (int df = 0; df < 4; df++) {
        accO[df][0] *= c0; accO[df][1] *= c1;
        accO[df][2] *= c2; accO[df][3] *= c3;
      }
    }
    {
      float m = mrow;
      float sum = 0.f;
      char* pw = (char*)Ps[w];
#pragma unroll
      for (int nf = 0; nf < 4; nf++) {
        float p0 = fexp2(s[nf][0] - m);
        float p1 = fexp2(s[nf][1] - m);
        float p2 = fexp2(s[nf][2] - m);
        float p3 = fexp2(s[nf][3] - m);
        sum += (p0 + p1) + (p2 + p3);
        unsigned w0 = pk2bf(p0, p1);
        unsigned w1 = pk2bf(p2, p3);
        *(uint64_t*)(pw + pwoff[nf]) = (uint64_t)w0 | ((uint64_t)w1 << 32);
      }
      lsum += sum;
    }

    // ---- O += P V
    const char* pb = (const char*)Ps[w];
    const char* vb = (const char*)Vs[cur];
    __builtin_amdgcn_s_setprio(1);
#pragma unroll
    for (int ks = 0; ks < 2; ks++) {
      bf16x8 ap = *(const bf16x8*)(pb + poff[ks]);
#pragma unroll
      for (int df = 0; df < 4; df++) {
        bf16x8 bv = *(const bf16x8*)(vb + voff[ks][df]);
        accO[df] = __builtin_amdgcn_mfma_f32_16x16x32_bf16(ap, bv, accO[df], 0, 0, 0);
      }
    }
    __builtin_amdgcn_s_setprio(0);
    __syncthreads();
  }

  // ---- epilogue: reduce per-lane lsum across the 4 lanes of each row
  lsum += __shfl_xor(lsum, 16, 64);
  lsum += __shfl_xor(lsum, 32, 64);

  if (partial) {
    int pbase = (((bh << 4) + (qt - 16)) << 1) + half;
    if (lg == 0) {
      Mpart[pbase * 64 + w * 16 + lr] = mrow;
      Lpart[pbase * 64 + w * 16 + lr] = lsum;
    }
    unsigned short* Od = Opart + (size_t)pbase * 4096;
#pragma unroll
    for (int df = 0; df < 4; df++)
#pragma unroll
      for (int r = 0; r < 4; r++)
        Od[(w * 16 + lg * 4 + r) * 64 + df * 16 + lr] = f2b(accO[df][r]);
  } else {
    int b = bh >> 4, h = bh & 15;
    float li = 1.0f / lsum;
    float l0 = __shfl(li, lg * 4 + 0, 64);
    float l1 = __shfl(li, lg * 4 + 1, 64);
    float l2 = __shfl(li, lg * 4 + 2, 64);
    float l3 = __shfl(li, lg * 4 + 3, 64);
    int qbase = qt * 64 + w * 16;
#pragma unroll
    for (int df = 0; df < 4; df++) {
      int d = df * 16 + lr;
      size_t ob = ((size_t)(b * NTOK + qbase + lg * 4)) * DMODEL + h * DHEAD + d;
      AO[ob + 0 * DMODEL] = f2b(accO[df][0] * l0);
      AO[ob + 1 * DMODEL] = f2b(accO[df][1] * l1);
      AO[ob + 2 * DMODEL] = f2b(accO[df][2] * l2);
      AO[ob + 3 * DMODEL] = f2b(accO[df][3] * l3);
    }
  }
}

// ---- merge two kv-halves for qt>=16 ----
__global__ __launch_bounds__(256) void k_merge(const unsigned short* __restrict__ Opart,
                                               const float* __restrict__ Mpart,
                                               const float* __restrict__ Lpart,
                                               unsigned short* __restrict__ AO) {
  int bh = blockIdx.x, qq = blockIdx.y;
  int t = threadIdx.x;
  int row = t >> 2, d0 = (t & 3) << 4;
  int p0 = ((bh << 4) + qq) << 1;
  float m1 = Mpart[p0 * 64 + row],       l1 = Lpart[p0 * 64 + row];
  float m2 = Mpart[(p0 + 1) * 64 + row], l2 = Lpart[(p0 + 1) * 64 + row];
  float mm = fmaxf(m1, m2);
  float s1 = fexp2(m1 - mm), s2 = fexp2(m2 - mm);
  float li = 1.0f / (l1 * s1 + l2 * s2);
  float a1 = s1 * li, a2 = s2 * li;
  const unsigned short* O1 = Opart + (size_t)p0 * 4096 + row * 64 + d0;
  const unsigned short* O2 = O1 + 4096;
  int qt = 16 + qq;
  int b = bh >> 4, h = bh & 15;
  unsigned short* dst = AO + ((size_t)(b * NTOK + qt * 64 + row)) * DMODEL + h * DHEAD + d0;
#pragma unroll
  for (int c = 0; c < 2; c++) {
    u16x8 v1 = *(const u16x8*)(O1 + c * 8);
    u16x8 v2 = *(const u16x8*)(O2 + c * 8);
    u16x8 o;
#pragma unroll
    for (int e = 0; e < 8; e++) {
      float f1 = __builtin_bit_cast(float, (unsigned)v1[e] << 16);
      float g1 = __builtin_bit_cast(float, (unsigned)v2[e] << 16);
      o[e] = f2b(f1 * a1 + g1 * a2);
    }
    *(u16x8*)(dst + c * 8) = o;
  }
}

// ---- out GEMM: BM=128 BN=64, depth-2 counted-vmcnt pipeline + T2 swizzle ----
#define OSTAGE(b, k0) do {                                   \
    gl16(Ag + (k0), &As[b][t * 8]);                          \
    gl16(Ag + (k0) + 64 * DMODEL, &As[b][(t + 256) * 8]);    \
    gl16(Bg + (k0), &Bs[b][t * 8]);                          \
  } while (0)

__global__ __launch_bounds__(256) void k_out_gemm(
    const unsigned short* __restrict__ A, const unsigned short* __restrict__ Bt,
    const float* __restrict__ bias, float* __restrict__ out) {
  __shared__ unsigned short As[3][128 * 32];
  __shared__ unsigned short Bs[3][64 * 32];
  int bm = blockIdx.x, bn = blockIdx.y;
  int t = threadIdx.x;
  int l = t & 63, w = t >> 6;
  int wr = w >> 1, wc = w & 1;
  int lr = l & 15, lg = l >> 4;
  f32x4 acc[4][2] = {};

  int srow = t >> 2;
  int scho = ((t & 3) ^ ((t >> 3) & 3)) * 8;
  const unsigned short* Ag = A + (size_t)(bm * 128 + srow) * DMODEL + scho;
  const unsigned short* Bg = Bt + (size_t)(bn * 64 + srow) * DMODEL + scho;
  int swz = (lr >> 1) & 3;

  OSTAGE(0, 0);
  OSTAGE(1, 32);

  for (int i = 0; i < 32; i++) {
    int cb = i % 3;
    if (i < 31) { asm volatile("s_waitcnt vmcnt(3)" ::: "memory"); }
    else        { asm volatile("s_waitcnt vmcnt(0)" ::: "memory"); }
    __builtin_amdgcn_s_barrier();
    __builtin_amdgcn_sched_barrier(0);
    if (i < 30) OSTAGE((i + 2) % 3, (i + 2) * 32);
    bf16x8 af[4], bfr[2];
#pragma unroll
    for (int ii = 0; ii < 4; ii++)
      af[ii] = *(const bf16x8*)&As[cb][(wr * 64 + ii * 16 + lr) * 32 + (lg ^ swz) * 8];
#pragma unroll
    for (int jj = 0; jj < 2; jj++)
      bfr[jj] = *(const bf16x8*)&Bs[cb][(wc * 32 + jj * 16 + lr) * 32 + (lg ^ swz) * 8];
    __builtin_amdgcn_s_setprio(1);
#pragma unroll
    for (int ii = 0; ii < 4; ii++)
#pragma unroll
      for (int jj = 0; jj < 2; jj++)
        acc[ii][jj] = __builtin_amdgcn_mfma_f32_16x16x32_bf16(af[ii], bfr[jj], acc[ii][jj], 0, 0, 0);
    __builtin_amdgcn_s_setprio(0);
  }
  int nc0 = bn * 64 + wc * 32;
#pragma unroll
  for (int i = 0; i < 4; i++)
#pragma unroll
    for (int r = 0; r < 4; r++) {
      int m = bm * 128 + wr * 64 + i * 16 + lg * 4 + r;
      float* orow = out + (size_t)m * DMODEL;
#pragma unroll
      for (int j = 0; j < 2; j++) {
        int col = nc0 + j * 16 + lr;
        orow[col] = acc[i][j][r] + bias[col];
      }
    }
}

extern "C" void kernel_launch(void* const* d_in, const int* in_sizes, int n_in,
                              void* d_out, int out_size, void* d_ws, size_t ws_size,
                              hipStream_t stream) {
  const float* x      = (const float*)d_in[0];
  const float* norm_w = (const float*)d_in[1];
  const float* w_qkv  = (const float*)d_in[2];
  const float* w_o    = (const float*)d_in[3];
  const float* b_o    = (const float*)d_in[4];
  const float* sin_t  = (const float*)d_in[5];
  const float* cos_t  = (const float*)d_in[6];
  float* out = (float*)d_out;

  char* ws = (char*)d_ws;
  unsigned short* xn    = (unsigned short*)(ws + (0u << 20));   // 8 MB  (dead after qkv)
  unsigned short* wqkvT = (unsigned short*)(ws + (8u << 20));   // 6 MB  (dead after qkv)
  unsigned short* woT   = (unsigned short*)(ws + (14u << 20));  // 2 MB
  unsigned short* Qh    = (unsigned short*)(ws + (16u << 20));  // 8 MB  [b][h][n][d]
  unsigned short* Kh    = (unsigned short*)(ws + (24u << 20));  // 8 MB  [b][h][n][d]
  unsigned short* VhT   = (unsigned short*)(ws + (32u << 20));  // 8 MB  [b][h][d][n]
  unsigned short* AO    = (unsigned short*)(ws + (40u << 20));  // 8 MB  [b][n][h*d]
  // attn partials reuse regions dead during k_attn (rewritten every call):
  unsigned short* Opart = (unsigned short*)(ws + (0u << 20));           // 8 MB in xn
  float*          Mpart = (float*)(ws + (8u << 20));                    // 256 KB in wqkvT
  float*          Lpart = (float*)(ws + (8u << 20) + (1u << 18));       // 256 KB in wqkvT

  hipLaunchKernelGGL(k_prep, dim3(NROWS + 768 + 256), dim3(256), 0, stream,
                     x, norm_w, xn, w_qkv, wqkvT, w_o, woT);
  hipLaunchKernelGGL(k_qkv_gemm, dim3(32, 24), dim3(256), 0, stream, xn, wqkvT, sin_t, cos_t, Qh, Kh, VhT);
  hipLaunchKernelGGL(k_attn, dim3(32, 48), dim3(256), 0, stream, Qh, Kh, VhT, AO, Opart, Mpart, Lpart);
  hipLaunchKernelGGL(k_merge, dim3(32, 16), dim3(256), 0, stream, Opart, Mpart, Lpart, AO);
  hipLaunchKernelGGL(k_out_gemm, dim3(32, 16), dim3(256), 0, stream, AO, woT, b_o, out);
}

// Round 19
// 112.281 us; speedup vs baseline: 1.1098x; 1.0093x over previous
//
#include <hip/hip_runtime.h>
#include <hip/hip_bf16.h>
#include <stdint.h>
#include <stddef.h>

#define NTOK   2048
#define NHEAD  16
#define DHEAD  64
#define DMODEL 1024
#define NROWS  4096      // B * NTOK
#define NQKV   3072
#define RMS_EPS 1.1920928955078125e-07f
// attention scale 1/8 with log2(e) folded in (scores in log2 domain)
#define QSCALE 0.1803368801111204f

typedef short bf16x8 __attribute__((ext_vector_type(8)));
typedef float f32x4  __attribute__((ext_vector_type(4)));
typedef unsigned short u16x4 __attribute__((ext_vector_type(4)));
typedef unsigned short u16x8 __attribute__((ext_vector_type(8)));

__device__ __forceinline__ unsigned short f2b(float f) {
  unsigned u = __builtin_bit_cast(unsigned, f);
  return (unsigned short)((u + 0x7fffu + ((u >> 16) & 1u)) >> 16);  // RNE
}

__device__ __forceinline__ unsigned pk2bf(float a, float b) {
  __hip_bfloat162 h = __float22bfloat162_rn(make_float2(a, b));
  unsigned u;
  __builtin_memcpy(&u, &h, 4);
  return u;
}

__device__ __forceinline__ float fexp2(float x) {
#if __has_builtin(__builtin_amdgcn_exp2f)
  return __builtin_amdgcn_exp2f(x);
#else
  float r;
  asm("v_exp_f32 %0, %1" : "=v"(r) : "v"(x));
  return r;
#endif
}

__device__ __forceinline__ void gl16(const void* g, void* l) {
  __builtin_amdgcn_global_load_lds((__attribute__((address_space(1))) void*)g,
                                   (__attribute__((address_space(3))) void*)l,
                                   16, 0, 0);
}

// ==== fused prep: rmsnorm (blocks 0..4095) + w_qkv transpose (4096..4863)
// ==== + w_o transpose (4864..5119) — one launch, concurrent execution.
__global__ __launch_bounds__(256) void k_prep(
    const float* __restrict__ x, const float* __restrict__ norm_w,
    unsigned short* __restrict__ xn,
    const float* __restrict__ w_qkv, unsigned short* __restrict__ wqkvT,
    const float* __restrict__ w_o, unsigned short* __restrict__ woT) {
  __shared__ float tile[64][65];
  int bid = blockIdx.x;
  int t = threadIdx.x;
  if (bid < NROWS) {
    // ---- rmsnorm row
    int row = bid;
    float4 v = ((const float4*)(x + (size_t)row * DMODEL))[t];
    float ss = v.x * v.x + v.y * v.y + v.z * v.z + v.w * v.w;
#pragma unroll
    for (int m = 1; m < 64; m <<= 1) ss += __shfl_xor(ss, m, 64);
    if ((t & 63) == 0) tile[0][t >> 6] = ss;
    __syncthreads();
    float tot = (tile[0][0] + tile[0][1]) + (tile[0][2] + tile[0][3]);
    float rs = rsqrtf(tot * (1.0f / DMODEL) + RMS_EPS);
    float4 wv = ((const float4*)norm_w)[t];
    u16x4 o;
    o.x = f2b(v.x * rs * wv.x);
    o.y = f2b(v.y * rs * wv.y);
    o.z = f2b(v.z * rs * wv.z);
    o.w = f2b(v.w * rs * wv.w);
    *(u16x4*)(xn + (size_t)row * DMODEL + t * 4) = o;
    return;
  }
  // ---- transpose+convert: W fp32 [K][Nw] -> Wt bf16 [Nw][K]
  const float* W;
  unsigned short* Wt;
  int Nw, bk, bn;
  if (bid < NROWS + 768) {
    int m = bid - NROWS;
    W = w_qkv; Wt = wqkvT; Nw = NQKV;
    bk = (m & 15) * 64; bn = (m >> 4) * 64;
  } else {
    int m = bid - NROWS - 768;
    W = w_o; Wt = woT; Nw = DMODEL;
    bk = (m & 15) * 64; bn = (m >> 4) * 64;
  }
  int tr = t >> 4;
  int tc = (t & 15) * 4;
#pragma unroll
  for (int rr = 0; rr < 64; rr += 16) {
    float4 v = *(const float4*)&W[(size_t)(bk + tr + rr) * Nw + bn + tc];
    tile[tr + rr][tc + 0] = v.x;
    tile[tr + rr][tc + 1] = v.y;
    tile[tr + rr][tc + 2] = v.z;
    tile[tr + rr][tc + 3] = v.w;
  }
  __syncthreads();
#pragma unroll
  for (int rr = 0; rr < 64; rr += 16) {
    int n = bn + tr + rr;
    u16x4 o;
    o.x = f2b(tile[tc + 0][tr + rr]);
    o.y = f2b(tile[tc + 1][tr + rr]);
    o.z = f2b(tile[tc + 2][tr + rr]);
    o.w = f2b(tile[tc + 3][tr + rr]);
    *(u16x4*)&Wt[(size_t)n * DMODEL + bk + tc] = o;
  }
}

// ------- QKV GEMM: 128x128, BK=32, depth-2 counted-vmcnt pipeline + T2 swizzle -------
// (Proven optimum: ~46 us, 0 bank conflicts, 3 blocks/CU.) NEW: T5 setprio around
// the MFMA cluster — 3 independent blocks/CU at staggered phases give the CU
// scheduler MFMA-vs-stage wave diversity to arbitrate (same regime as attn's +4-7%).
#define QSTAGE(b, k0) do {                                   \
    gl16(Ag + (k0), &As[b][t * 8]);                          \
    gl16(Ag + (k0) + 64 * DMODEL, &As[b][(t + 256) * 8]);    \
    gl16(Bg + (k0), &Bs[b][t * 8]);                          \
    gl16(Bg + (k0) + 64 * DMODEL, &Bs[b][(t + 256) * 8]);    \
  } while (0)

__global__ __launch_bounds__(256) void k_qkv_gemm(
    const unsigned short* __restrict__ A, const unsigned short* __restrict__ Bt,
    const float* __restrict__ sin_t, const float* __restrict__ cos_t,
    unsigned short* __restrict__ Qh, unsigned short* __restrict__ Kh,
    unsigned short* __restrict__ VhT) {
  __shared__ unsigned short As[3][128 * 32];
  __shared__ unsigned short Bs[3][128 * 32];
  int bm = blockIdx.x, bn = blockIdx.y;
  int t = threadIdx.x;
  int l = t & 63, w = t >> 6;
  int wr = w >> 1, wc = w & 1;
  int lr = l & 15, lg = l >> 4;
  f32x4 acc[4][4] = {};

  int srow = t >> 2;
  int scho = ((t & 3) ^ ((t >> 3) & 3)) * 8;          // pre-swizzled source chunk
  const unsigned short* Ag = A + (size_t)(bm * 128 + srow) * DMODEL + scho;
  const unsigned short* Bg = Bt + (size_t)(bn * 128 + srow) * DMODEL + scho;
  int swz = (lr >> 1) & 3;

  QSTAGE(0, 0);
  QSTAGE(1, 32);

  for (int i = 0; i < 32; i++) {
    int cb = i % 3;
    if (i < 31) { asm volatile("s_waitcnt vmcnt(4)" ::: "memory"); }
    else        { asm volatile("s_waitcnt vmcnt(0)" ::: "memory"); }
    __builtin_amdgcn_s_barrier();
    __builtin_amdgcn_sched_barrier(0);
    if (i < 30) QSTAGE((i + 2) % 3, (i + 2) * 32);
    bf16x8 af[4], bfr[4];
#pragma unroll
    for (int ii = 0; ii < 4; ii++)
      af[ii] = *(const bf16x8*)&As[cb][(wr * 64 + ii * 16 + lr) * 32 + (lg ^ swz) * 8];
#pragma unroll
    for (int jj = 0; jj < 4; jj++)
      bfr[jj] = *(const bf16x8*)&Bs[cb][(wc * 64 + jj * 16 + lr) * 32 + (lg ^ swz) * 8];
    __builtin_amdgcn_s_setprio(1);
#pragma unroll
    for (int ii = 0; ii < 4; ii++)
#pragma unroll
      for (int jj = 0; jj < 4; jj++)
        acc[ii][jj] = __builtin_amdgcn_mfma_f32_16x16x32_bf16(af[ii], bfr[jj], acc[ii][jj], 0, 0, 0);
    __builtin_amdgcn_s_setprio(0);
  }

  int nc0 = bn * 128 + wc * 64;
  int which = nc0 >> 10;
  int h = (nc0 & 1023) >> 6;
#pragma unroll
  for (int i = 0; i < 4; i++) {
#pragma unroll
    for (int r = 0; r < 4; r++) {
      int m = bm * 128 + wr * 64 + i * 16 + lg * 4 + r;
      int b = m >> 11;
      int n = m & (NTOK - 1);
      if (which == 2) {
#pragma unroll
        for (int j = 0; j < 4; j++) {
          int d = j * 16 + lr;
          VhT[((size_t)((b * NHEAD + h) * DHEAD) + d) * NTOK + n] = f2b(acc[i][j][r]);
        }
      } else {
        size_t obase = ((size_t)(b * NHEAD + h) * NTOK + n) * DHEAD;
        unsigned short* dst = which ? Kh : Qh;
        float qs = which ? 1.0f : QSCALE;
#pragma unroll
        for (int j = 0; j < 2; j++) {
          int d = j * 16 + lr;
          float t1 = acc[i][j][r];
          float t2 = acc[i][j + 2][r];
          float c1 = cos_t[n * DHEAD + d],      s1 = sin_t[n * DHEAD + d];
          float c2 = cos_t[n * DHEAD + d + 32], s2 = sin_t[n * DHEAD + d + 32];
          dst[obase + d]      = f2b((t1 * c1 - t2 * s1) * qs);
          dst[obase + d + 32] = f2b((t2 * c2 + t1 * s2) * qs);
        }
      }
    }
  }
}

// ---- flash attention (causal) with kv-split: 48 work items per bh, sorted desc ----
// QBLK=64 proven structure + deferred cross-lane max + per-lane lsum.
#define SL(q, a, b) ((q) | ((a) << 6) | ((b) << 12))
__constant__ int SLOTS[48] = {
  SL(31,0,16), SL(31,16,32), SL(30,15,31), SL(15,0,16),
  SL(30,0,15), SL(29,0,15),  SL(29,15,30), SL(28,14,29), SL(14,0,15),
  SL(28,0,14), SL(27,0,14),  SL(27,14,28), SL(26,13,27), SL(13,0,14),
  SL(26,0,13), SL(25,0,13),  SL(25,13,26), SL(24,12,25), SL(12,0,13),
  SL(24,0,12), SL(23,0,12),  SL(23,12,24), SL(22,11,23), SL(11,0,12),
  SL(22,0,11), SL(21,0,11),  SL(21,11,22), SL(20,10,21), SL(10,0,11),
  SL(20,0,10), SL(19,0,10),  SL(19,10,20), SL(18,9,19),  SL(9,0,10),
  SL(18,0,9),  SL(17,0,9),   SL(17,9,18),  SL(16,8,17),  SL(8,0,9),
  SL(16,0,8),  SL(7,0,8),    SL(6,0,7),    SL(5,0,6),    SL(4,0,5),
  SL(3,0,4),   SL(2,0,3),    SL(1,0,2),    SL(0,0,1)
};

__global__ __launch_bounds__(256, 4) void k_attn(
    const unsigned short* __restrict__ Qh, const unsigned short* __restrict__ Kh,
    const unsigned short* __restrict__ VhT, unsigned short* __restrict__ AO,
    unsigned short* __restrict__ Opart, float* __restrict__ Mpart,
    float* __restrict__ Lpart) {
  int bh = blockIdx.x;
  int sv = SLOTS[blockIdx.y];
  int qt = sv & 63, kt0 = (sv >> 6) & 63, kt1 = sv >> 12;
  bool partial = (kt0 != 0) || (kt1 != qt + 1);
  int half = (kt0 != 0) ? 1 : 0;
  int t = threadIdx.x;
  int l = t & 63, w = t >> 6;
  int lr = l & 15, lg = l >> 4;

  __shared__ unsigned short Ks[2][64 * 64];
  __shared__ unsigned short Vs[2][64 * 64];
  __shared__ unsigned short Ps[4][16 * 64];

  const unsigned short* Qb = Qh  + (size_t)bh * NTOK * DHEAD;
  const unsigned short* Kb = Kh  + (size_t)bh * NTOK * DHEAD;
  const unsigned short* Vb = VhT + (size_t)bh * DHEAD * NTOK;

  int qrow = qt * 64 + w * 16 + lr;
  bf16x8 aq0 = *(const bf16x8*)&Qb[(size_t)qrow * DHEAD + lg * 8];
  bf16x8 aq1 = *(const bf16x8*)&Qb[(size_t)qrow * DHEAD + 32 + lg * 8];

  f32x4 accO[4] = {};
  float mrow = -1e38f;    // running max (log2 domain), row-uniform invariant
  float lsum = 0.f;       // per-lane partial; reduced at epilogue

  int srow = t >> 3;
  int spc  = t & 7;
  int sc0  = (spc ^ (srow & 7)) * 8;
  int sc1  = (spc ^ ((srow + 32) & 7)) * 8;

  int koff[4][2], voff[2][4], poff[2], pwoff[4];
#pragma unroll
  for (int nf = 0; nf < 4; nf++) {
    int krow = nf * 16 + lr;
    koff[nf][0] = krow * 128 + ((lg * 16) ^ ((krow & 7) << 4));
    koff[nf][1] = krow * 128 + ((lg * 16 + 64) ^ ((krow & 7) << 4));
    pwoff[nf] = lr * 128 + ((nf * 32 + lg * 8) ^ ((lr & 7) << 4));
  }
#pragma unroll
  for (int ks = 0; ks < 2; ks++) {
    poff[ks] = lr * 128 + ((lg * 16 + ks * 64) ^ ((lr & 7) << 4));
#pragma unroll
    for (int df = 0; df < 4; df++) {
      int col = df * 16 + lr;
      voff[ks][df] = col * 128 + ((lg * 16 + ks * 64) ^ ((col & 7) << 4));
    }
  }

  {
    int kv0 = kt0 * 64;
    gl16(Kb + (size_t)(kv0 + srow) * DHEAD + sc0, &Ks[0][t * 8]);
    gl16(Kb + (size_t)(kv0 + srow + 32) * DHEAD + sc1, &Ks[0][(t + 256) * 8]);
    gl16(Vb + (size_t)srow * NTOK + kv0 + sc0, &Vs[0][t * 8]);
    gl16(Vb + (size_t)(srow + 32) * NTOK + kv0 + sc1, &Vs[0][(t + 256) * 8]);
  }
  __syncthreads();

  for (int kt = kt0; kt < kt1; ++kt) {
    int cur = (kt - kt0) & 1, nxt = cur ^ 1;
    int kv0 = kt * 64;

    if (kt + 1 < kt1) {
      int kvn = kv0 + 64;
      gl16(Kb + (size_t)(kvn + srow) * DHEAD + sc0, &Ks[nxt][t * 8]);
      gl16(Kb + (size_t)(kvn + srow + 32) * DHEAD + sc1, &Ks[nxt][(t + 256) * 8]);
      gl16(Vb + (size_t)srow * NTOK + kvn + sc0, &Vs[nxt][t * 8]);
      gl16(Vb + (size_t)(srow + 32) * NTOK + kvn + sc1, &Vs[nxt][(t + 256) * 8]);
    }

    // ---- S^T = K Q^T
    const char* kb = (const char*)Ks[cur];
    f32x4 s[4];
    __builtin_amdgcn_s_setprio(1);
#pragma unroll
    for (int nf = 0; nf < 4; nf++) {
      bf16x8 bk0 = *(const bf16x8*)(kb + koff[nf][0]);
      bf16x8 bk1 = *(const bf16x8*)(kb + koff[nf][1]);
      f32x4 z = {};
      z = __builtin_amdgcn_mfma_f32_16x16x32_bf16(bk0, aq0, z, 0, 0, 0);
      s[nf] = __builtin_amdgcn_mfma_f32_16x16x32_bf16(bk1, aq1, z, 0, 0, 0);
    }
    __builtin_amdgcn_s_setprio(0);

    if (kt == qt) {
      int qr = qt * 64 + w * 16 + lr;
#pragma unroll
      for (int nf = 0; nf < 4; nf++)
#pragma unroll
        for (int r = 0; r < 4; r++)
          if (kv0 + nf * 16 + lg * 4 + r > qr) s[nf][r] = -1e30f;
    }

    // ---- online softmax: in-lane max only; cross-lane reduce deferred
    float t1m = fmaxf(fmaxf(s[0][0], s[0][1]), s[0][2]);
    float t2m = fmaxf(fmaxf(s[0][3], s[1][0]), s[1][1]);
    float t3m = fmaxf(fmaxf(s[1][2], s[1][3]), s[2][0]);
    float t4m = fmaxf(fmaxf(s[2][1], s[2][2]), s[2][3]);
    float t5m = fmaxf(fmaxf(s[3][0], s[3][1]), s[3][2]);
    float pl = fmaxf(fmaxf(fmaxf(t1m, t2m), t3m), fmaxf(fmaxf(t4m, t5m), s[3][3]));
    if (__any(pl > mrow + 8.0f)) {
      float pm = fmaxf(pl, __shfl_xor(pl, 16, 64));
      pm = fmaxf(pm, __shfl_xor(pm, 32, 64));
      float mnew = fmaxf(mrow, pm);
      float corr = fexp2(mrow - mnew);
      mrow = mnew;
      lsum *= corr;
      float c0 = __shfl(corr, lg * 4 + 0, 64);
      float c1 = __shfl(corr, lg * 4 + 1, 64);
      float c2 = __shfl(corr, lg * 4 + 2, 64);
      float c3 = __shfl(corr, lg * 4 + 3, 64);
#pragma unroll
      for (int df = 0; df < 4; df++) {
        accO[df][0] *= c0; accO[df][1] *= c1;
        accO[df][2] *= c2; accO[df][3] *= c3;
      }
    }
    {
      float m = mrow;
      float sum = 0.f;
      char* pw = (char*)Ps[w];
#pragma unroll
      for (int nf = 0; nf < 4; nf++) {
        float p0 = fexp2(s[nf][0] - m);
        float p1 = fexp2(s[nf][1] - m);
        float p2 = fexp2(s[nf][2] - m);
        float p3 = fexp2(s[nf][3] - m);
        sum += (p0 + p1) + (p2 + p3);
        unsigned w0 = pk2bf(p0, p1);
        unsigned w1 = pk2bf(p2, p3);
        *(uint64_t*)(pw + pwoff[nf]) = (uint64_t)w0 | ((uint64_t)w1 << 32);
      }
      lsum += sum;
    }

    // ---- O += P V
    const char* pb = (const char*)Ps[w];
    const char* vb = (const char*)Vs[cur];
    __builtin_amdgcn_s_setprio(1);
#pragma unroll
    for (int ks = 0; ks < 2; ks++) {
      bf16x8 ap = *(const bf16x8*)(pb + poff[ks]);
#pragma unroll
      for (int df = 0; df < 4; df++) {
        bf16x8 bv = *(const bf16x8*)(vb + voff[ks][df]);
        accO[df] = __builtin_amdgcn_mfma_f32_16x16x32_bf16(ap, bv, accO[df], 0, 0, 0);
      }
    }
    __builtin_amdgcn_s_setprio(0);
    __syncthreads();
  }

  // ---- epilogue: reduce per-lane lsum across the 4 lanes of each row
  lsum += __shfl_xor(lsum, 16, 64);
  lsum += __shfl_xor(lsum, 32, 64);

  if (partial) {
    int pbase = (((bh << 4) + (qt - 16)) << 1) + half;
    if (lg == 0) {
      Mpart[pbase * 64 + w * 16 + lr] = mrow;
      Lpart[pbase * 64 + w * 16 + lr] = lsum;
    }
    unsigned short* Od = Opart + (size_t)pbase * 4096;
#pragma unroll
    for (int df = 0; df < 4; df++)
#pragma unroll
      for (int r = 0; r < 4; r++)
        Od[(w * 16 + lg * 4 + r) * 64 + df * 16 + lr] = f2b(accO[df][r]);
  } else {
    int b = bh >> 4, h = bh & 15;
    float li = 1.0f / lsum;
    float l0 = __shfl(li, lg * 4 + 0, 64);
    float l1 = __shfl(li, lg * 4 + 1, 64);
    float l2 = __shfl(li, lg * 4 + 2, 64);
    float l3 = __shfl(li, lg * 4 + 3, 64);
    int qbase = qt * 64 + w * 16;
#pragma unroll
    for (int df = 0; df < 4; df++) {
      int d = df * 16 + lr;
      size_t ob = ((size_t)(b * NTOK + qbase + lg * 4)) * DMODEL + h * DHEAD + d;
      AO[ob + 0 * DMODEL] = f2b(accO[df][0] * l0);
      AO[ob + 1 * DMODEL] = f2b(accO[df][1] * l1);
      AO[ob + 2 * DMODEL] = f2b(accO[df][2] * l2);
      AO[ob + 3 * DMODEL] = f2b(accO[df][3] * l3);
    }
  }
}

// ---- merge two kv-halves for qt>=16 ----
__global__ __launch_bounds__(256) void k_merge(const unsigned short* __restrict__ Opart,
                                               const float* __restrict__ Mpart,
                                               const float* __restrict__ Lpart,
                                               unsigned short* __restrict__ AO) {
  int bh = blockIdx.x, qq = blockIdx.y;
  int t = threadIdx.x;
  int row = t >> 2, d0 = (t & 3) << 4;
  int p0 = ((bh << 4) + qq) << 1;
  float m1 = Mpart[p0 * 64 + row],       l1 = Lpart[p0 * 64 + row];
  float m2 = Mpart[(p0 + 1) * 64 + row], l2 = Lpart[(p0 + 1) * 64 + row];
  float mm = fmaxf(m1, m2);
  float s1 = fexp2(m1 - mm), s2 = fexp2(m2 - mm);
  float li = 1.0f / (l1 * s1 + l2 * s2);
  float a1 = s1 * li, a2 = s2 * li;
  const unsigned short* O1 = Opart + (size_t)p0 * 4096 + row * 64 + d0;
  const unsigned short* O2 = O1 + 4096;
  int qt = 16 + qq;
  int b = bh >> 4, h = bh & 15;
  unsigned short* dst = AO + ((size_t)(b * NTOK + qt * 64 + row)) * DMODEL + h * DHEAD + d0;
#pragma unroll
  for (int c = 0; c < 2; c++) {
    u16x8 v1 = *(const u16x8*)(O1 + c * 8);
    u16x8 v2 = *(const u16x8*)(O2 + c * 8);
    u16x8 o;
#pragma unroll
    for (int e = 0; e < 8; e++) {
      float f1 = __builtin_bit_cast(float, (unsigned)v1[e] << 16);
      float g1 = __builtin_bit_cast(float, (unsigned)v2[e] << 16);
      o[e] = f2b(f1 * a1 + g1 * a2);
    }
    *(u16x8*)(dst + c * 8) = o;
  }
}

// ---- out GEMM: BM=128 BN=64, depth-2 counted-vmcnt pipeline + T2 swizzle ----
#define OSTAGE(b, k0) do {                                   \
    gl16(Ag + (k0), &As[b][t * 8]);                          \
    gl16(Ag + (k0) + 64 * DMODEL, &As[b][(t + 256) * 8]);    \
    gl16(Bg + (k0), &Bs[b][t * 8]);                          \
  } while (0)

__global__ __launch_bounds__(256) void k_out_gemm(
    const unsigned short* __restrict__ A, const unsigned short* __restrict__ Bt,
    const float* __restrict__ bias, float* __restrict__ out) {
  __shared__ unsigned short As[3][128 * 32];
  __shared__ unsigned short Bs[3][64 * 32];
  int bm = blockIdx.x, bn = blockIdx.y;
  int t = threadIdx.x;
  int l = t & 63, w = t >> 6;
  int wr = w >> 1, wc = w & 1;
  int lr = l & 15, lg = l >> 4;
  f32x4 acc[4][2] = {};

  int srow = t >> 2;
  int scho = ((t & 3) ^ ((t >> 3) & 3)) * 8;
  const unsigned short* Ag = A + (size_t)(bm * 128 + srow) * DMODEL + scho;
  const unsigned short* Bg = Bt + (size_t)(bn * 64 + srow) * DMODEL + scho;
  int swz = (lr >> 1) & 3;

  OSTAGE(0, 0);
  OSTAGE(1, 32);

  for (int i = 0; i < 32; i++) {
    int cb = i % 3;
    if (i < 31) { asm volatile("s_waitcnt vmcnt(3)" ::: "memory"); }
    else        { asm volatile("s_waitcnt vmcnt(0)" ::: "memory"); }
    __builtin_amdgcn_s_barrier();
    __builtin_amdgcn_sched_barrier(0);
    if (i < 30) OSTAGE((i + 2) % 3, (i + 2) * 32);
    bf16x8 af[4], bfr[2];
#pragma unroll
    for (int ii = 0; ii < 4; ii++)
      af[ii] = *(const bf16x8*)&As[cb][(wr * 64 + ii * 16 + lr) * 32 + (lg ^ swz) * 8];
#pragma unroll
    for (int jj = 0; jj < 2; jj++)
      bfr[jj] = *(const bf16x8*)&Bs[cb][(wc * 32 + jj * 16 + lr) * 32 + (lg ^ swz) * 8];
    __builtin_amdgcn_s_setprio(1);
#pragma unroll
    for (int ii = 0; ii < 4; ii++)
#pragma unroll
      for (int jj = 0; jj < 2; jj++)
        acc[ii][jj] = __builtin_amdgcn_mfma_f32_16x16x32_bf16(af[ii], bfr[jj], acc[ii][jj], 0, 0, 0);
    __builtin_amdgcn_s_setprio(0);
  }
  int nc0 = bn * 64 + wc * 32;
#pragma unroll
  for (int i = 0; i < 4; i++)
#pragma unroll
    for (int r = 0; r < 4; r++) {
      int m = bm * 128 + wr * 64 + i * 16 + lg * 4 + r;
      float* orow = out + (size_t)m * DMODEL;
#pragma unroll
      for (int j = 0; j < 2; j++) {
        int col = nc0 + j * 16 + lr;
        orow[col] = acc[i][j][r] + bias[col];
      }
    }
}

extern "C" void kernel_launch(void* const* d_in, const int* in_sizes, int n_in,
                              void* d_out, int out_size, void* d_ws, size_t ws_size,
                              hipStream_t stream) {
  const float* x      = (const float*)d_in[0];
  const float* norm_w = (const float*)d_in[1];
  const float* w_qkv  = (const float*)d_in[2];
  const float* w_o    = (const float*)d_in[3];
  const float* b_o    = (const float*)d_in[4];
  const float* sin_t  = (const float*)d_in[5];
  const float* cos_t  = (const float*)d_in[6];
  float* out = (float*)d_out;

  char* ws = (char*)d_ws;
  unsigned short* xn    = (unsigned short*)(ws + (0u << 20));   // 8 MB  (dead after qkv)
  unsigned short* wqkvT = (unsigned short*)(ws + (8u << 20));   // 6 MB  (dead after qkv)
  unsigned short* woT   = (unsigned short*)(ws + (14u << 20));  // 2 MB
  unsigned short* Qh    = (unsigned short*)(ws + (16u << 20));  // 8 MB  [b][h][n][d]
  unsigned short* Kh    = (unsigned short*)(ws + (24u << 20));  // 8 MB  [b][h][n][d]
  unsigned short* VhT   = (unsigned short*)(ws + (32u << 20));  // 8 MB  [b][h][d][n]
  unsigned short* AO    = (unsigned short*)(ws + (40u << 20));  // 8 MB  [b][n][h*d]
  // attn partials reuse regions dead during k_attn (rewritten every call):
  unsigned short* Opart = (unsigned short*)(ws + (0u << 20));           // 8 MB in xn
  float*          Mpart = (float*)(ws + (8u << 20));                    // 256 KB in wqkvT
  float*          Lpart = (float*)(ws + (8u << 20) + (1u << 18));       // 256 KB in wqkvT

  hipLaunchKernelGGL(k_prep, dim3(NROWS + 768 + 256), dim3(256), 0, stream,
                     x, norm_w, xn, w_qkv, wqkvT, w_o, woT);
  hipLaunchKernelGGL(k_qkv_gemm, dim3(32, 24), dim3(256), 0, stream, xn, wqkvT, sin_t, cos_t, Qh, Kh, VhT);
  hipLaunchKernelGGL(k_attn, dim3(32, 48), dim3(256), 0, stream, Qh, Kh, VhT, AO, Opart, Mpart, Lpart);
  hipLaunchKernelGGL(k_merge, dim3(32, 16), dim3(256), 0, stream, Opart, Mpart, Lpart, AO);
  hipLaunchKernelGGL(k_out_gemm, dim3(32, 16), dim3(256), 0, stream, AO, woT, b_o, out);
}